// Round 9
// baseline (104.767 us; speedup 1.0000x reference)
//
#include <hip/hip_runtime.h>

// Problem constants: b=32, d=256, h=32, w=128
#define BB 32
#define DD 256
#define HW 4096
#define DHW (DD * HW)
#define NSLICE (BB * DD)       // 8192 (b,d) slices of 4096 floats
#define EPS 1e-5f

#define FNBLK 256              // 1 block/CU; capacity >= 2 blocks/CU -> co-resident, 2x margin
#define FSPB (NSLICE / FNBLK)  // 32 slices per block, all sharing one b

// ws layout (floats): [0,8192) slice sum | [8192,16384) slice sumsq
//                     | [16384,16416) per-b count | [16448] barrier counter (uint)
#define WS_SUM 0
#define WS_SQ  NSLICE
#define WS_CNT (2 * NSLICE)
#define WS_CTR (2 * NSLICE + 64)

typedef float floatx4 __attribute__((ext_vector_type(4)));

__global__ void __launch_bounds__(1024)
fused2_kernel(const float* __restrict__ x, const int* __restrict__ mask,
              const float* __restrict__ gamma, const float* __restrict__ beta,
              float* __restrict__ ws, float* __restrict__ out) {
    const int blk = blockIdx.x;
    const int tid = threadIdx.x;           // 0..1023
    const int wave = tid >> 6, lane = tid & 63;
    const int slice0 = blk * FSPB;
    const int b = slice0 >> 8;             // 32 divides 256 -> all 32 slices share b
    const int d0 = slice0 & 255;           // 0,32,64,...,224

    __shared__ float ssum[FSPB][16], ssq[FSPB][16], scnt[16];
    __shared__ float s_scale[FSPB], s_bias[FSPB];

    // This b's mask: one int4 per thread (4096 ints = 1024 int4), in regs,
    // reused by phase 1 and phase 3.
    const int4 mv = reinterpret_cast<const int4*>(mask + b * HW)[tid];

    // Per-b unmasked count (only the d0==0 block publishes it)
    {
        float c = (mv.x ? 0.f : 1.f) + (mv.y ? 0.f : 1.f)
                + (mv.z ? 0.f : 1.f) + (mv.w ? 0.f : 1.f);
#pragma unroll
        for (int off = 32; off > 0; off >>= 1) c += __shfl_down(c, off);
        if (lane == 0) scnt[wave] = c;
    }

    // ---- Phase 1: per-slice partial sums (one float4 per thread per slice) ----
    const float4* xb = reinterpret_cast<const float4*>(x + (size_t)slice0 * HW);
#pragma unroll
    for (int s = 0; s < FSPB; ++s) {
        float4 xv = xb[s * 1024 + tid];
        float sum = 0.f, sq = 0.f;
        if (!mv.x) { sum += xv.x; sq += xv.x * xv.x; }
        if (!mv.y) { sum += xv.y; sq += xv.y * xv.y; }
        if (!mv.z) { sum += xv.z; sq += xv.z * xv.z; }
        if (!mv.w) { sum += xv.w; sq += xv.w * xv.w; }
#pragma unroll
        for (int off = 32; off > 0; off >>= 1) {
            sum += __shfl_down(sum, off);
            sq  += __shfl_down(sq, off);
        }
        if (lane == 0) { ssum[s][wave] = sum; ssq[s][wave] = sq; }
    }
    __syncthreads();
    // Reduce 16 wave-partials per slice: threads 0..511, one 16-group per slice.
    if (tid < 512) {
        const int s = tid >> 4, w = tid & 15;
        float ts = ssum[s][w], tq = ssq[s][w];
#pragma unroll
        for (int off = 8; off > 0; off >>= 1) {
            ts += __shfl_down(ts, off, 16);
            tq += __shfl_down(tq, off, 16);
        }
        if (w == 0) {
            ws[WS_SUM + slice0 + s] = ts;
            ws[WS_SQ + slice0 + s] = tq;
        }
    }
    if (tid == 0 && d0 == 0) {
        float tc = 0.f;
#pragma unroll
        for (int i = 0; i < 16; ++i) tc += scnt[i];
        ws[WS_CNT + b] = tc;
    }
    __syncthreads();   // drain all waves' ws stores (each wave: s_waitcnt vmcnt(0))

    // ---- Hand-rolled grid barrier (normal launch; all 256 blocks co-resident) ----
    unsigned* ctr = reinterpret_cast<unsigned*>(ws + WS_CTR);
    if (tid == 0) {
        __hip_atomic_fetch_add(ctr, 1u, __ATOMIC_RELEASE, __HIP_MEMORY_SCOPE_AGENT);
        while (__hip_atomic_load(ctr, __ATOMIC_ACQUIRE, __HIP_MEMORY_SCOPE_AGENT)
               < (unsigned)FNBLK) {
            __builtin_amdgcn_s_sleep(2);
        }
    }
    __syncthreads();

    // ---- Phase 2: finalize this block's 32 channels ----
    // Group g (32 lanes) owns channel d0+g; lane bl gathers b-partial bl.
    // Agent-scope atomic loads: coherent across XCD L2s.
    {
        const int g = tid >> 5, bl = tid & 31;
        const int ch = d0 + g;
        float ps = __hip_atomic_load(&ws[WS_SUM + bl * DD + ch],
                                     __ATOMIC_RELAXED, __HIP_MEMORY_SCOPE_AGENT);
        float pq = __hip_atomic_load(&ws[WS_SQ + bl * DD + ch],
                                     __ATOMIC_RELAXED, __HIP_MEMORY_SCOPE_AGENT);
        float pc = __hip_atomic_load(&ws[WS_CNT + bl],
                                     __ATOMIC_RELAXED, __HIP_MEMORY_SCOPE_AGENT);
#pragma unroll
        for (int off = 16; off > 0; off >>= 1) {
            ps += __shfl_down(ps, off, 32);
            pq += __shfl_down(pq, off, 32);
            pc += __shfl_down(pc, off, 32);
        }
        if (bl == 0) {
            pc = fmaxf(pc, 1.0f);
            const float mean = ps / pc;
            const float var = fmaxf(pq / pc - mean * mean, 0.0f);
            const float sc = rsqrtf(var + EPS) * gamma[ch];
            s_scale[g] = sc;
            s_bias[g] = beta[ch] - mean * sc;
        }
    }
    __syncthreads();

    // ---- Phase 3: normalize own slices (x re-read = in-kernel L3 hit; nt-store) ----
    floatx4* ob = reinterpret_cast<floatx4*>(out + (size_t)slice0 * HW);
#pragma unroll
    for (int s = 0; s < FSPB; ++s) {
        const float sc = s_scale[s], bi = s_bias[s];
        float4 xv = xb[s * 1024 + tid];
        floatx4 o;
        o.x = mv.x ? xv.x : xv.x * sc + bi;
        o.y = mv.y ? xv.y : xv.y * sc + bi;
        o.z = mv.z ? xv.z : xv.z * sc + bi;
        o.w = mv.w ? xv.w : xv.w * sc + bi;
        __builtin_nontemporal_store(o, &ob[s * 1024 + tid]);
    }
}

extern "C" void kernel_launch(void* const* d_in, const int* in_sizes, int n_in,
                              void* d_out, int out_size, void* d_ws, size_t ws_size,
                              hipStream_t stream) {
    const float* x     = (const float*)d_in[0];
    const int*   mask  = (const int*)d_in[1];
    const float* gamma = (const float*)d_in[2];
    const float* beta  = (const float*)d_in[3];
    float* out = (float*)d_out;
    float* ws  = (float*)d_ws;

    // Zero the barrier counter (ws is poisoned once, never re-poisoned).
    hipMemsetAsync((char*)d_ws + WS_CTR * sizeof(float), 0, sizeof(unsigned), stream);
    fused2_kernel<<<FNBLK, 1024, 0, stream>>>(x, mask, gamma, beta, ws, out);
}

// Round 10
// 64.947 us; speedup vs baseline: 1.6131x; 1.6131x over previous
//
#include <hip/hip_runtime.h>

// Problem constants: b=32, d=256, h=32, w=128
#define BB 32
#define DD 256
#define HW 4096
#define DHW (DD * HW)        // 2^20
#define EPS 1e-5f

typedef float floatx4 __attribute__((ext_vector_type(4)));

// One block per channel d. 1024 threads; thread t owns hw-positions [4t, 4t+4)
// across all 32 batches. All data a block touches belongs to ITS channel ->
// phase A is pure register accumulation (no cross-lane ops between loads).
// Global count: every block reads the full mask (shared, L2/L3-resident) and
// computes the identical global count independently -> no inter-block comms.
__global__ void __launch_bounds__(1024)
channel_kernel(const float* __restrict__ x, const int* __restrict__ mask,
               const float* __restrict__ gamma, const float* __restrict__ beta,
               float* __restrict__ out) {
    const int d = blockIdx.x;            // channel
    const int tid = threadIdx.x;         // 0..1023
    const int wave = tid >> 6, lane = tid & 63;

    const float4* __restrict__ xv4 = reinterpret_cast<const float4*>(x);
    const int4*   __restrict__ mv4 = reinterpret_cast<const int4*>(mask);
    const int xbase = d * 1024 + tid;    // float4 index of (b=0, d, 4*tid)

    // ---- Phase A: pure-streaming masked accumulation ----
    float sum = 0.f, sq = 0.f, cnt = 0.f;
#pragma unroll 8
    for (int b = 0; b < BB; ++b) {
        float4 xv = xv4[b * (DHW / 4) + xbase];
        int4  mv = mv4[b * 1024 + tid];
        if (!mv.x) { sum += xv.x; sq += xv.x * xv.x; cnt += 1.f; }
        if (!mv.y) { sum += xv.y; sq += xv.y * xv.y; cnt += 1.f; }
        if (!mv.z) { sum += xv.z; sq += xv.z * xv.z; cnt += 1.f; }
        if (!mv.w) { sum += xv.w; sq += xv.w * xv.w; cnt += 1.f; }
    }

    // ---- Phase B: block reduce (1024 -> 1), compute scale/bias ----
    __shared__ float rsum[16], rsq[16], rcnt[16];
    __shared__ float s_scale, s_bias;
#pragma unroll
    for (int off = 32; off > 0; off >>= 1) {
        sum += __shfl_down(sum, off);
        sq  += __shfl_down(sq, off);
        cnt += __shfl_down(cnt, off);
    }
    if (lane == 0) { rsum[wave] = sum; rsq[wave] = sq; rcnt[wave] = cnt; }
    __syncthreads();
    if (tid < 16) {
        float ts = rsum[tid], tq = rsq[tid], tc = rcnt[tid];
#pragma unroll
        for (int off = 8; off > 0; off >>= 1) {
            ts += __shfl_down(ts, off, 16);
            tq += __shfl_down(tq, off, 16);
            tc += __shfl_down(tc, off, 16);
        }
        if (tid == 0) {
            tc = fmaxf(tc, 1.0f);
            const float mean = ts / tc;
            const float var = fmaxf(tq / tc - mean * mean, 0.0f);
            const float sc = rsqrtf(var + EPS) * gamma[d];
            s_scale = sc;
            s_bias = beta[d] - mean * sc;
        }
    }
    __syncthreads();
    const float sc = s_scale, bi = s_bias;

    // ---- Phase C: re-read own 512 KB (in-kernel L3 hit) + nt-store out ----
    floatx4* __restrict__ ov4 = reinterpret_cast<floatx4*>(out);
#pragma unroll 8
    for (int b = 0; b < BB; ++b) {
        float4 xv = xv4[b * (DHW / 4) + xbase];
        int4  mv = mv4[b * 1024 + tid];
        floatx4 o;
        o.x = mv.x ? xv.x : xv.x * sc + bi;
        o.y = mv.y ? xv.y : xv.y * sc + bi;
        o.z = mv.z ? xv.z : xv.z * sc + bi;
        o.w = mv.w ? xv.w : xv.w * sc + bi;
        __builtin_nontemporal_store(o, &ov4[b * (DHW / 4) + xbase]);
    }
}

extern "C" void kernel_launch(void* const* d_in, const int* in_sizes, int n_in,
                              void* d_out, int out_size, void* d_ws, size_t ws_size,
                              hipStream_t stream) {
    const float* x     = (const float*)d_in[0];
    const int*   mask  = (const int*)d_in[1];
    const float* gamma = (const float*)d_in[2];
    const float* beta  = (const float*)d_in[3];
    float* out = (float*)d_out;

    channel_kernel<<<DD, 1024, 0, stream>>>(x, mask, gamma, beta, out);
}